// Round 1
// baseline (3293.305 us; speedup 1.0000x reference)
//
#include <hip/hip_runtime.h>
#include <hip/hip_bf16.h>

#define NN 100000
#define EE 1000000
#define GG 512
#define HH 64
#define LL 7
#define NH (NN*HH)
#define GH (GG*HH)
#define EPS_GEN 1e-7f
#define EPS_BN 1e-5f

__device__ __constant__ int c_atom_off[9] = {0,119,124,136,148,158,164,170,172};

// h[n][c] = sum_f atom_table[x[n][f]+off_f][c] + vn0[c]
__global__ void k_atom_enc(const float* __restrict__ atom_table,
                           const float* __restrict__ vn0,
                           const int* __restrict__ x,
                           float* __restrict__ h) {
    int tid = blockIdx.x * blockDim.x + threadIdx.x;
    int n = tid >> 6, c = tid & 63;
    if (n >= NN) return;
    float acc = vn0[c];
    const int* xr = x + n * 9;
    #pragma unroll
    for (int f = 0; f < 9; ++f) {
        int idx = xr[f] + c_atom_off[f];
        acc += atom_table[idx * HH + c];
    }
    h[tid] = acc;
}

__global__ void k_vn_init(const float* __restrict__ vn0, float* __restrict__ vn) {
    int tid = blockIdx.x * blockDim.x + threadIdx.x;
    if (tid < GH) vn[tid] = vn0[tid & 63];
}

// per-channel sum & sumsq over `rows` rows -> stats[0..63]=sum, stats[64..127]=sumsq
__global__ void k_bnstats(const float* __restrict__ in, int rows, float* __restrict__ stats) {
    __shared__ float s_sum[4][64], s_sq[4][64];
    int c = threadIdx.x & 63;
    int w = threadIdx.x >> 6;
    int nw = blockDim.x >> 6;
    float sum = 0.f, sq = 0.f;
    for (int r = blockIdx.x * nw + w; r < rows; r += gridDim.x * nw) {
        float v = in[r * HH + c];
        sum += v;
        sq = fmaf(v, v, sq);
    }
    s_sum[w][c] = sum; s_sq[w][c] = sq;
    __syncthreads();
    if (w == 0) {
        sum = s_sum[0][c] + s_sum[1][c] + s_sum[2][c] + s_sum[3][c];
        sq  = s_sq[0][c]  + s_sq[1][c]  + s_sq[2][c]  + s_sq[3][c];
        atomicAdd(&stats[c], sum);
        atomicAdd(&stats[64 + c], sq);
    }
}

// h2 = relu(bn(h)); also vt[batch[n]] += h2[n]  (vt pre-initialized to vn)
__global__ void k_bn_relu_vt(const float* __restrict__ h, const float* __restrict__ stats,
                             const float* __restrict__ gamma, const float* __restrict__ beta,
                             const int* __restrict__ batch, float rows_inv,
                             float* __restrict__ h2, float* __restrict__ vt) {
    int tid = blockIdx.x * blockDim.x + threadIdx.x;
    int n = tid >> 6, c = tid & 63;
    if (n >= NN) return;
    float mu = stats[c] * rows_inv;
    float var = stats[64 + c] * rows_inv - mu * mu;
    float inv = rsqrtf(var + EPS_BN);
    float v = (h[tid] - mu) * inv * gamma[c] + beta[c];
    v = fmaxf(v, 0.f);
    h2[tid] = v;
    atomicAdd(&vt[batch[n] * HH + c], v);
}

// out = bn(in) (optional relu), rows x 64
__global__ void k_bn_act(const float* __restrict__ in, const float* __restrict__ stats,
                         const float* __restrict__ gamma, const float* __restrict__ beta,
                         int rows, float rows_inv, int do_relu, float* __restrict__ out) {
    int tid = blockIdx.x * blockDim.x + threadIdx.x;
    if (tid >= rows * HH) return;
    int c = tid & 63;
    float mu = stats[c] * rows_inv;
    float var = stats[64 + c] * rows_inv - mu * mu;
    float inv = rsqrtf(var + EPS_BN);
    float v = (in[tid] - mu) * inv * gamma[c] + beta[c];
    if (do_relu) v = fmaxf(v, 0.f);
    out[tid] = v;
}

// out[r] = in[r] @ W + b   (rows x 64) @ (64 x 64); W staged in LDS; wave-per-row
__global__ void k_gemm_small(const float* __restrict__ in, const float* __restrict__ W,
                             const float* __restrict__ b, float* __restrict__ out, int rows) {
    __shared__ float sW[64 * 64];
    for (int i = threadIdx.x; i < 4096; i += blockDim.x) sW[i] = W[i];
    __syncthreads();
    int lane = threadIdx.x & 63;
    int w = threadIdx.x >> 6, nw = blockDim.x >> 6;
    for (int r = blockIdx.x * nw + w; r < rows; r += gridDim.x * nw) {
        float va = in[r * HH + lane];
        float acc = b[lane];
        #pragma unroll
        for (int k = 0; k < 64; ++k)
            acc = fmaf(__shfl(va, k, 64), sW[k * 64 + lane], acc);
        out[r * HH + lane] = acc;
    }
}

// out[r] = (hin[r] + m[r]) @ W + b (+ res[r]); in-place safe (wave owns whole row)
__global__ void k_conv_gemm(const float* hin, const float* m,
                            const float* __restrict__ W, const float* __restrict__ b,
                            const float* res, float* out) {
    __shared__ float sW[64 * 64];
    for (int i = threadIdx.x; i < 4096; i += blockDim.x) sW[i] = W[i];
    __syncthreads();
    int lane = threadIdx.x & 63;
    int w = threadIdx.x >> 6, nw = blockDim.x >> 6;
    for (int r = blockIdx.x * nw + w; r < NN; r += gridDim.x * nw) {
        float va = hin[r * HH + lane] + m[r * HH + lane];
        float acc = b[lane];
        #pragma unroll
        for (int k = 0; k < 64; ++k)
            acc = fmaf(__shfl(va, k, 64), sW[k * 64 + lane], acc);
        if (res) acc += res[r * HH + lane];
        out[r * HH + lane] = acc;
    }
}

// h2[n] += vn[batch[n]]
__global__ void k_add_vn(float* __restrict__ h2, const float* __restrict__ vn,
                         const int* __restrict__ batch) {
    int tid = blockIdx.x * blockDim.x + threadIdx.x;
    int n = tid >> 6, c = tid & 63;
    if (n >= NN) return;
    h2[tid] += vn[batch[n] * HH + c];
}

// m[dst] += relu(hin[src] + bond_emb(edge_attr)) + eps ; wave-per-edge
__global__ void k_messages(const float* __restrict__ hin, const int* __restrict__ edge_index,
                           const int* __restrict__ edge_attr, const float* __restrict__ bond_table,
                           float* __restrict__ m) {
    __shared__ float sB[13 * 64];
    for (int i = threadIdx.x; i < 13 * 64; i += blockDim.x) sB[i] = bond_table[i];
    __syncthreads();
    int lane = threadIdx.x & 63;
    int w = threadIdx.x >> 6, nw = blockDim.x >> 6;
    for (int e = blockIdx.x * nw + w; e < EE; e += gridDim.x * nw) {
        int src = edge_index[e];
        int dst = edge_index[EE + e];
        int a0 = edge_attr[e * 3 + 0];
        int a1 = edge_attr[e * 3 + 1];
        int a2 = edge_attr[e * 3 + 2];
        float emb = sB[a0 * 64 + lane] + sB[(a1 + 5) * 64 + lane] + sB[(a2 + 11) * 64 + lane];
        float v = fmaxf(hin[src * HH + lane] + emb, 0.f) + EPS_GEN;
        atomicAdd(&m[dst * HH + lane], v);
    }
}

// out[batch[n]] += bn(h[n]) (no relu); cnt[batch[n]] += 1 (lane 0)
__global__ void k_bn_pool(const float* __restrict__ h, const float* __restrict__ stats,
                          const float* __restrict__ gamma, const float* __restrict__ beta,
                          const int* __restrict__ batch,
                          float* __restrict__ out, float* __restrict__ cnt) {
    int tid = blockIdx.x * blockDim.x + threadIdx.x;
    int n = tid >> 6, c = tid & 63;
    if (n >= NN) return;
    float mu = stats[c] * (1.f / NN);
    float var = stats[64 + c] * (1.f / NN) - mu * mu;
    float inv = rsqrtf(var + EPS_BN);
    float v = (h[tid] - mu) * inv * gamma[c] + beta[c];
    int g = batch[n];
    atomicAdd(&out[g * HH + c], v);
    if (c == 0) atomicAdd(&cnt[g], 1.0f);
}

__global__ void k_div(float* __restrict__ out, const float* __restrict__ cnt) {
    int tid = blockIdx.x * blockDim.x + threadIdx.x;
    if (tid >= GH) return;
    out[tid] /= fmaxf(cnt[tid >> 6], 1.0f);
}

extern "C" void kernel_launch(void* const* d_in, const int* in_sizes, int n_in,
                              void* d_out, int out_size, void* d_ws, size_t ws_size,
                              hipStream_t stream) {
    const float* atom_table = (const float*)d_in[0];
    const float* bond_table = (const float*)d_in[1];
    const float* vn0   = (const float*)d_in[2];
    const float* gcn_W = (const float*)d_in[3];
    const float* gcn_b = (const float*)d_in[4];
    const float* ng    = (const float*)d_in[5];
    const float* nb    = (const float*)d_in[6];
    const float* vn_W1 = (const float*)d_in[7];
    const float* vn_b1 = (const float*)d_in[8];
    const float* vn_g1 = (const float*)d_in[9];
    const float* vn_be1= (const float*)d_in[10];
    const float* vn_W2 = (const float*)d_in[11];
    const float* vn_b2 = (const float*)d_in[12];
    const float* vn_g2 = (const float*)d_in[13];
    const float* vn_be2= (const float*)d_in[14];
    const int* x          = (const int*)d_in[15];
    const int* edge_index = (const int*)d_in[16];
    const int* edge_attr  = (const int*)d_in[17];
    const int* batch      = (const int*)d_in[18];

    float* ws = (float*)d_ws;
    float* h   = ws;                  // NH
    float* h2  = ws + (size_t)NH;     // NH
    float* m   = ws + (size_t)2*NH;   // NH
    float* vn  = ws + (size_t)3*NH;   // GH
    float* vt  = vn + GH;             // GH
    float* t   = vt + GH;             // GH
    float* z   = t + GH;              // GH
    float* stats  = z + GH;           // 128
    float* stats2 = stats + 128;      // 128
    float* cnt    = stats2 + 128;     // GG

    const int blkN  = NH / 256;          // 25000 blocks, thread per (n,c)
    const int blkG  = (GH + 255) / 256;  // 128 blocks
    float* outp = (float*)d_out;

    k_atom_enc<<<blkN, 256, 0, stream>>>(atom_table, vn0, x, h);
    k_vn_init<<<blkG, 256, 0, stream>>>(vn0, vn);

    // layer 0 conv (no residual): h = (h + m0) @ W0 + b0
    hipMemsetAsync(m, 0, (size_t)NH * 4, stream);
    k_messages<<<8192, 256, 0, stream>>>(h, edge_index, edge_attr, bond_table, m);
    k_conv_gemm<<<2048, 256, 0, stream>>>(h, m, gcn_W, gcn_b, nullptr, h);

    for (int l = 1; l < LL; ++l) {
        const float* g0 = ng + (size_t)(l - 1) * HH;
        const float* b0 = nb + (size_t)(l - 1) * HH;
        hipMemsetAsync(stats, 0, 128 * 4, stream);
        k_bnstats<<<256, 256, 0, stream>>>(h, NN, stats);
        hipMemcpyAsync(vt, vn, (size_t)GH * 4, hipMemcpyDeviceToDevice, stream);
        k_bn_relu_vt<<<blkN, 256, 0, stream>>>(h, stats, g0, b0, batch, 1.f / NN, h2, vt);

        // virtual-node MLP: vn = relu(bn(relu(bn(vt@W1+b1)) @ W2 + b2))
        k_gemm_small<<<16, 256, 0, stream>>>(vt, vn_W1 + (size_t)(l - 1) * 4096,
                                             vn_b1 + (size_t)(l - 1) * HH, t, GG);
        hipMemsetAsync(stats2, 0, 128 * 4, stream);
        k_bnstats<<<8, 256, 0, stream>>>(t, GG, stats2);
        k_bn_act<<<blkG, 256, 0, stream>>>(t, stats2, vn_g1 + (size_t)(l - 1) * HH,
                                           vn_be1 + (size_t)(l - 1) * HH, GG, 1.f / GG, 1, z);
        k_gemm_small<<<16, 256, 0, stream>>>(z, vn_W2 + (size_t)(l - 1) * 4096,
                                             vn_b2 + (size_t)(l - 1) * HH, t, GG);
        hipMemsetAsync(stats2, 0, 128 * 4, stream);
        k_bnstats<<<8, 256, 0, stream>>>(t, GG, stats2);
        k_bn_act<<<blkG, 256, 0, stream>>>(t, stats2, vn_g2 + (size_t)(l - 1) * HH,
                                           vn_be2 + (size_t)(l - 1) * HH, GG, 1.f / GG, 1, vn);

        k_add_vn<<<blkN, 256, 0, stream>>>(h2, vn, batch);

        hipMemsetAsync(m, 0, (size_t)NH * 4, stream);
        k_messages<<<8192, 256, 0, stream>>>(h2, edge_index, edge_attr, bond_table, m);
        k_conv_gemm<<<2048, 256, 0, stream>>>(h2, m, gcn_W + (size_t)l * 4096,
                                              gcn_b + (size_t)l * HH, h, h);
    }

    // final BN + mean pool
    hipMemsetAsync(stats, 0, 128 * 4, stream);
    k_bnstats<<<256, 256, 0, stream>>>(h, NN, stats);
    hipMemsetAsync(outp, 0, (size_t)GH * 4, stream);
    hipMemsetAsync(cnt, 0, (size_t)GG * 4, stream);
    k_bn_pool<<<blkN, 256, 0, stream>>>(h, stats, ng + (size_t)6 * HH, nb + (size_t)6 * HH,
                                        batch, outp, cnt);
    k_div<<<blkG, 256, 0, stream>>>(outp, cnt);
}

// Round 2
// 2263.460 us; speedup vs baseline: 1.4550x; 1.4550x over previous
//
#include <hip/hip_runtime.h>
#include <hip/hip_bf16.h>

#define NN 100000
#define EE 1000000
#define GG 512
#define HH 64
#define LL 7
#define NH (NN*HH)
#define GH (GG*HH)
#define EPS_GEN 1e-7f
#define EPS_BN 1e-5f
#define SCAN_BLKS 98   // ceil(NN/1024)

__device__ __constant__ int c_atom_off[9] = {0,119,124,136,148,158,164,170,172};

// h[n][c] = sum_f atom_table[x[n][f]+off_f][c] + vn0[c]
__global__ void k_atom_enc(const float* __restrict__ atom_table,
                           const float* __restrict__ vn0,
                           const int* __restrict__ x,
                           float* __restrict__ h) {
    int tid = blockIdx.x * blockDim.x + threadIdx.x;
    int n = tid >> 6, c = tid & 63;
    if (n >= NN) return;
    float acc = vn0[c];
    const int* xr = x + n * 9;
    #pragma unroll
    for (int f = 0; f < 9; ++f) {
        int idx = xr[f] + c_atom_off[f];
        acc += atom_table[idx * HH + c];
    }
    h[tid] = acc;
}

__global__ void k_vn_init(const float* __restrict__ vn0, float* __restrict__ vn) {
    int tid = blockIdx.x * blockDim.x + threadIdx.x;
    if (tid < GH) vn[tid] = vn0[tid & 63];
}

// ---------------- CSR build (once per call, reused by all 7 layers) ----------------

__global__ void k_count(const int* __restrict__ edge_index, int* __restrict__ cur) {
    int e = blockIdx.x * blockDim.x + threadIdx.x;
    if (e >= EE) return;
    atomicAdd(&cur[edge_index[EE + e]], 1);
}

// block-local exclusive scan: 1024 elements/block (256 thr x 4)
__global__ void k_scan1(const int* __restrict__ cnt, int* __restrict__ rp, int* __restrict__ part) {
    __shared__ int s[256];
    int t = threadIdx.x, blk = blockIdx.x;
    int base = blk * 1024 + t * 4;
    int v0 = 0, v1 = 0, v2 = 0, v3 = 0;
    if (base + 3 < NN) {
        int4 q = *(const int4*)(cnt + base);
        v0 = q.x; v1 = q.y; v2 = q.z; v3 = q.w;
    } else {
        if (base + 0 < NN) v0 = cnt[base + 0];
        if (base + 1 < NN) v1 = cnt[base + 1];
        if (base + 2 < NN) v2 = cnt[base + 2];
        if (base + 3 < NN) v3 = cnt[base + 3];
    }
    int s4 = v0 + v1 + v2 + v3;
    s[t] = s4;
    __syncthreads();
    for (int off = 1; off < 256; off <<= 1) {
        int x = (t >= off) ? s[t - off] : 0;
        __syncthreads();
        s[t] += x;
        __syncthreads();
    }
    int excl = s[t] - s4;
    if (t == 255) part[blk] = s[255];
    if (base + 0 < NN) rp[base + 0] = excl;
    if (base + 1 < NN) rp[base + 1] = excl + v0;
    if (base + 2 < NN) rp[base + 2] = excl + v0 + v1;
    if (base + 3 < NN) rp[base + 3] = excl + v0 + v1 + v2;
}

__global__ void k_scan2(int* __restrict__ part) {
    __shared__ int s[128];
    int t = threadIdx.x;
    int v = (t < SCAN_BLKS) ? part[t] : 0;
    s[t] = v;
    __syncthreads();
    for (int off = 1; off < 128; off <<= 1) {
        int x = (t >= off) ? s[t - off] : 0;
        __syncthreads();
        s[t] += x;
        __syncthreads();
    }
    if (t < SCAN_BLKS) part[t] = s[t] - v;   // exclusive block offsets
}

__global__ void k_scan3(int* __restrict__ rp, const int* __restrict__ part) {
    int i = blockIdx.x * blockDim.x + threadIdx.x;
    if (i < NN) rp[i] += part[i >> 10];
    if (i == 0) rp[NN] = EE;   // total edges is a compile-time constant
}

// edges[slot] = {src, packed_attr}; slot = rp[dst] + running cursor
__global__ void k_fill(const int* __restrict__ edge_index, const int* __restrict__ edge_attr,
                       const int* __restrict__ rp, int* __restrict__ cur,
                       int2* __restrict__ edges) {
    int e = blockIdx.x * blockDim.x + threadIdx.x;
    if (e >= EE) return;
    int src = edge_index[e];
    int dst = edge_index[EE + e];
    int pa = edge_attr[e * 3] | (edge_attr[e * 3 + 1] << 3) | (edge_attr[e * 3 + 2] << 6);
    int slot = rp[dst] + atomicAdd(&cur[dst], 1);
    edges[slot] = make_int2(src, pa);
}

// ---------------- fused message aggregation + conv GEMM (+residual) ----------------
// wave per dst node: acc = sum_e relu(gsrc[src_e] + bond_emb_e) + eps   (atomic-free)
// then out[n] = (rsrc[n] + acc) @ W + b (+ res[n])
__global__ void k_conv_fused(const float* __restrict__ gsrc, const float* __restrict__ rsrc,
                             const float* __restrict__ res,
                             const int* __restrict__ rp, const int2* __restrict__ edges,
                             const float* __restrict__ bond,
                             const float* __restrict__ W, const float* __restrict__ b,
                             float* __restrict__ out) {
    __shared__ float sW[64 * 64];
    __shared__ float sB[13 * 64];
    for (int i = threadIdx.x; i < 4096; i += 256) sW[i] = W[i];
    for (int i = threadIdx.x; i < 832; i += 256) sB[i] = bond[i];
    __syncthreads();
    int lane = threadIdx.x & 63;
    int n = blockIdx.x * 4 + (threadIdx.x >> 6);
    if (n >= NN) return;
    int beg = rp[n], end = rp[n + 1];
    float acc = 0.f;
    int e = beg;
    for (; e + 2 <= end; e += 2) {          // 2 edges/iter: two gathers in flight
        int2 e0 = edges[e];
        int2 e1 = edges[e + 1];
        float h0 = gsrc[(size_t)e0.x * 64 + lane];
        float h1 = gsrc[(size_t)e1.x * 64 + lane];
        float emb0 = sB[(e0.y & 7) * 64 + lane] + sB[(5 + ((e0.y >> 3) & 7)) * 64 + lane]
                   + sB[(11 + (e0.y >> 6)) * 64 + lane];
        float emb1 = sB[(e1.y & 7) * 64 + lane] + sB[(5 + ((e1.y >> 3) & 7)) * 64 + lane]
                   + sB[(11 + (e1.y >> 6)) * 64 + lane];
        acc += fmaxf(h0 + emb0, 0.f) + EPS_GEN;
        acc += fmaxf(h1 + emb1, 0.f) + EPS_GEN;
    }
    if (e < end) {
        int2 e0 = edges[e];
        float h0 = gsrc[(size_t)e0.x * 64 + lane];
        float emb0 = sB[(e0.y & 7) * 64 + lane] + sB[(5 + ((e0.y >> 3) & 7)) * 64 + lane]
                   + sB[(11 + (e0.y >> 6)) * 64 + lane];
        acc += fmaxf(h0 + emb0, 0.f) + EPS_GEN;
    }
    float va = rsrc[(size_t)n * 64 + lane] + acc;
    float r = b[lane];
    #pragma unroll
    for (int k = 0; k < 64; ++k)
        r = fmaf(__shfl(va, k, 64), sW[k * 64 + lane], r);
    if (res) r += res[(size_t)n * 64 + lane];
    out[(size_t)n * 64 + lane] = r;
}

// ---------------- BN / pooling ----------------

__global__ void k_bnstats(const float* __restrict__ in, int rows, float* __restrict__ stats) {
    __shared__ float s_sum[4][64], s_sq[4][64];
    int c = threadIdx.x & 63;
    int w = threadIdx.x >> 6;
    int nw = blockDim.x >> 6;
    float sum = 0.f, sq = 0.f;
    for (int r = blockIdx.x * nw + w; r < rows; r += gridDim.x * nw) {
        float v = in[r * HH + c];
        sum += v;
        sq = fmaf(v, v, sq);
    }
    s_sum[w][c] = sum; s_sq[w][c] = sq;
    __syncthreads();
    if (w == 0) {
        sum = s_sum[0][c] + s_sum[1][c] + s_sum[2][c] + s_sum[3][c];
        sq  = s_sq[0][c]  + s_sq[1][c]  + s_sq[2][c]  + s_sq[3][c];
        atomicAdd(&stats[c], sum);
        atomicAdd(&stats[64 + c], sq);
    }
}

// h2 = relu(bn(h)); vt[batch[n]] += h2[n] using run-length aggregation (batch sorted)
__global__ void k_bn_relu_vt2(const float* __restrict__ h, const float* __restrict__ stats,
                              const float* __restrict__ gamma, const float* __restrict__ beta,
                              const int* __restrict__ batch,
                              float* __restrict__ h2, float* __restrict__ vt) {
    int lane = threadIdx.x & 63;
    int w = blockIdx.x * 4 + (threadIdx.x >> 6);
    int n0 = w * 128;
    if (n0 >= NN) return;
    int n1 = min(n0 + 128, NN);
    float mu = stats[lane] * (1.f / NN);
    float var = stats[64 + lane] * (1.f / NN) - mu * mu;
    float inv = rsqrtf(var + EPS_BN) * gamma[lane];
    float bet = beta[lane];
    float acc = 0.f;
    int gcur = batch[n0];
    for (int n = n0; n < n1; ++n) {
        float v = fmaxf((h[(size_t)n * 64 + lane] - mu) * inv + bet, 0.f);
        h2[(size_t)n * 64 + lane] = v;
        int g = batch[n];
        if (g != gcur) {
            atomicAdd(&vt[(size_t)gcur * 64 + lane], acc);
            acc = 0.f; gcur = g;
        }
        acc += v;
    }
    atomicAdd(&vt[(size_t)gcur * 64 + lane], acc);
}

// out = bn/act of small rows x 64
__global__ void k_bn_act(const float* __restrict__ in, const float* __restrict__ stats,
                         const float* __restrict__ gamma, const float* __restrict__ beta,
                         int rows, float rows_inv, int do_relu, float* __restrict__ out) {
    int tid = blockIdx.x * blockDim.x + threadIdx.x;
    if (tid >= rows * HH) return;
    int c = tid & 63;
    float mu = stats[c] * rows_inv;
    float var = stats[64 + c] * rows_inv - mu * mu;
    float inv = rsqrtf(var + EPS_BN);
    float v = (in[tid] - mu) * inv * gamma[c] + beta[c];
    if (do_relu) v = fmaxf(v, 0.f);
    out[tid] = v;
}

// out[r] = in[r] @ W + b  (rows x 64)
__global__ void k_gemm_small(const float* __restrict__ in, const float* __restrict__ W,
                             const float* __restrict__ b, float* __restrict__ out, int rows) {
    __shared__ float sW[64 * 64];
    for (int i = threadIdx.x; i < 4096; i += blockDim.x) sW[i] = W[i];
    __syncthreads();
    int lane = threadIdx.x & 63;
    int w = threadIdx.x >> 6, nw = blockDim.x >> 6;
    for (int r = blockIdx.x * nw + w; r < rows; r += gridDim.x * nw) {
        float va = in[r * HH + lane];
        float acc = b[lane];
        #pragma unroll
        for (int k = 0; k < 64; ++k)
            acc = fmaf(__shfl(va, k, 64), sW[k * 64 + lane], acc);
        out[r * HH + lane] = acc;
    }
}

// h2[n] += vn[batch[n]]
__global__ void k_add_vn(float* __restrict__ h2, const float* __restrict__ vn,
                         const int* __restrict__ batch) {
    int tid = blockIdx.x * blockDim.x + threadIdx.x;
    int n = tid >> 6, c = tid & 63;
    if (n >= NN) return;
    h2[tid] += vn[batch[n] * HH + c];
}

// final BN + mean-pool numerator + counts, run-length aggregated
__global__ void k_pool2(const float* __restrict__ h, const float* __restrict__ stats,
                        const float* __restrict__ gamma, const float* __restrict__ beta,
                        const int* __restrict__ batch,
                        float* __restrict__ out, float* __restrict__ cnt) {
    int lane = threadIdx.x & 63;
    int w = blockIdx.x * 4 + (threadIdx.x >> 6);
    int n0 = w * 128;
    if (n0 >= NN) return;
    int n1 = min(n0 + 128, NN);
    float mu = stats[lane] * (1.f / NN);
    float var = stats[64 + lane] * (1.f / NN) - mu * mu;
    float inv = rsqrtf(var + EPS_BN) * gamma[lane];
    float bet = beta[lane];
    float acc = 0.f;
    int run = 0;
    int gcur = batch[n0];
    for (int n = n0; n < n1; ++n) {
        float v = (h[(size_t)n * 64 + lane] - mu) * inv + bet;
        int g = batch[n];
        if (g != gcur) {
            atomicAdd(&out[(size_t)gcur * 64 + lane], acc);
            if (lane == 0) atomicAdd(&cnt[gcur], (float)run);
            acc = 0.f; run = 0; gcur = g;
        }
        acc += v; run++;
    }
    atomicAdd(&out[(size_t)gcur * 64 + lane], acc);
    if (lane == 0) atomicAdd(&cnt[gcur], (float)run);
}

__global__ void k_div(float* __restrict__ out, const float* __restrict__ cnt) {
    int tid = blockIdx.x * blockDim.x + threadIdx.x;
    if (tid >= GH) return;
    out[tid] /= fmaxf(cnt[tid >> 6], 1.0f);
}

extern "C" void kernel_launch(void* const* d_in, const int* in_sizes, int n_in,
                              void* d_out, int out_size, void* d_ws, size_t ws_size,
                              hipStream_t stream) {
    const float* atom_table = (const float*)d_in[0];
    const float* bond_table = (const float*)d_in[1];
    const float* vn0   = (const float*)d_in[2];
    const float* gcn_W = (const float*)d_in[3];
    const float* gcn_b = (const float*)d_in[4];
    const float* ng    = (const float*)d_in[5];
    const float* nb    = (const float*)d_in[6];
    const float* vn_W1 = (const float*)d_in[7];
    const float* vn_b1 = (const float*)d_in[8];
    const float* vn_g1 = (const float*)d_in[9];
    const float* vn_be1= (const float*)d_in[10];
    const float* vn_W2 = (const float*)d_in[11];
    const float* vn_b2 = (const float*)d_in[12];
    const float* vn_g2 = (const float*)d_in[13];
    const float* vn_be2= (const float*)d_in[14];
    const int* x          = (const int*)d_in[15];
    const int* edge_index = (const int*)d_in[16];
    const int* edge_attr  = (const int*)d_in[17];
    const int* batch      = (const int*)d_in[18];

    float* ws = (float*)d_ws;
    float* hA  = ws;                   // NH  (encoder out; reused as h2 from layer 1)
    float* hB  = ws + (size_t)NH;      // NH  (running h)
    float* h2  = hA;                   // alias: encoder output dead after layer 0
    float* vn  = ws + (size_t)2 * NH;  // GH
    float* vt  = vn + GH;              // GH
    float* t   = vt + GH;              // GH
    float* z   = t + GH;               // GH
    float* stats  = z + GH;            // 128
    float* stats2 = stats + 128;       // 128
    float* cnt    = stats2 + 128;      // GG
    int*   rp     = (int*)(cnt + GG);  // NN+1
    int*   cur    = rp + (NN + 1);     // NN
    int*   part   = cur + NN;          // 128
    int2*  edges  = (int2*)(part + 128); // EE int2 (8 MB)

    const int blkN = NH / 256;            // 25000
    const int blkG = (GH + 255) / 256;    // 128
    const int blkE = (EE + 255) / 256;    // 3907
    const int blkW = (NN + 511) / 512;    // 196 (wave-per-128-node-chunk kernels)
    const int blkC = (NN + 3) / 4;        // 25000 (wave-per-node conv)
    float* outp = (float*)d_out;

    k_atom_enc<<<blkN, 256, 0, stream>>>(atom_table, vn0, x, hA);
    k_vn_init<<<blkG, 256, 0, stream>>>(vn0, vn);

    // ---- CSR build (amortized over 7 layers) ----
    hipMemsetAsync(cur, 0, (size_t)NN * 4, stream);
    k_count<<<blkE, 256, 0, stream>>>(edge_index, cur);
    k_scan1<<<SCAN_BLKS, 256, 0, stream>>>(cur, rp, part);
    k_scan2<<<1, 128, 0, stream>>>(part);
    k_scan3<<<(NN + 255) / 256, 256, 0, stream>>>(rp, part);
    hipMemsetAsync(cur, 0, (size_t)NN * 4, stream);
    k_fill<<<blkE, 256, 0, stream>>>(edge_index, edge_attr, rp, cur, edges);

    // ---- layer 0: h = (hA + agg(hA)) @ W0 + b0  -> hB ----
    k_conv_fused<<<blkC, 256, 0, stream>>>(hA, hA, nullptr, rp, edges, bond_table,
                                           gcn_W, gcn_b, hB);

    for (int l = 1; l < LL; ++l) {
        const float* g0 = ng + (size_t)(l - 1) * HH;
        const float* b0 = nb + (size_t)(l - 1) * HH;
        hipMemsetAsync(stats, 0, 128 * 4, stream);
        k_bnstats<<<256, 256, 0, stream>>>(hB, NN, stats);
        hipMemcpyAsync(vt, vn, (size_t)GH * 4, hipMemcpyDeviceToDevice, stream);
        k_bn_relu_vt2<<<blkW, 256, 0, stream>>>(hB, stats, g0, b0, batch, h2, vt);

        // virtual-node MLP: vn = relu(bn(relu(bn(vt@W1+b1)) @ W2 + b2))
        k_gemm_small<<<16, 256, 0, stream>>>(vt, vn_W1 + (size_t)(l - 1) * 4096,
                                             vn_b1 + (size_t)(l - 1) * HH, t, GG);
        hipMemsetAsync(stats2, 0, 128 * 4, stream);
        k_bnstats<<<8, 256, 0, stream>>>(t, GG, stats2);
        k_bn_act<<<blkG, 256, 0, stream>>>(t, stats2, vn_g1 + (size_t)(l - 1) * HH,
                                           vn_be1 + (size_t)(l - 1) * HH, GG, 1.f / GG, 1, z);
        k_gemm_small<<<16, 256, 0, stream>>>(z, vn_W2 + (size_t)(l - 1) * 4096,
                                             vn_b2 + (size_t)(l - 1) * HH, t, GG);
        hipMemsetAsync(stats2, 0, 128 * 4, stream);
        k_bnstats<<<8, 256, 0, stream>>>(t, GG, stats2);
        k_bn_act<<<blkG, 256, 0, stream>>>(t, stats2, vn_g2 + (size_t)(l - 1) * HH,
                                           vn_be2 + (size_t)(l - 1) * HH, GG, 1.f / GG, 1, vn);

        k_add_vn<<<blkN, 256, 0, stream>>>(h2, vn, batch);

        // h = (h2 + agg(h2)) @ W_l + b_l + h   (in-place on hB: gathers read h2 only)
        k_conv_fused<<<blkC, 256, 0, stream>>>(h2, h2, hB, rp, edges, bond_table,
                                               gcn_W + (size_t)l * 4096,
                                               gcn_b + (size_t)l * HH, hB);
    }

    // ---- final BN + mean pool ----
    hipMemsetAsync(stats, 0, 128 * 4, stream);
    k_bnstats<<<256, 256, 0, stream>>>(hB, NN, stats);
    hipMemsetAsync(outp, 0, (size_t)GH * 4, stream);
    hipMemsetAsync(cnt, 0, (size_t)GG * 4, stream);
    k_pool2<<<blkW, 256, 0, stream>>>(hB, stats, ng + (size_t)6 * HH, nb + (size_t)6 * HH,
                                      batch, outp, cnt);
    k_div<<<blkG, 256, 0, stream>>>(outp, cnt);
}

// Round 3
// 2163.008 us; speedup vs baseline: 1.5226x; 1.0464x over previous
//
#include <hip/hip_runtime.h>
#include <hip/hip_bf16.h>

#define NN 100000
#define EE 1000000
#define GG 512
#define HH 64
#define LL 7
#define NH (NN*HH)
#define GH (GG*HH)
#define EPS_GEN 1e-7f
#define EPS_BN 1e-5f
#define SCAN_BLKS 98   // ceil(NN/1024)

#define CONV_BLOCKS 1024
#define CONV_WPB 8
#define CONV_NWAVES (CONV_BLOCKS*CONV_WPB)                 // 8192
#define CONV_CHUNK ((NN + CONV_NWAVES - 1)/CONV_NWAVES)    // 13

__device__ __constant__ int c_atom_off[9] = {0,119,124,136,148,158,164,170,172};

__global__ void k_atom_enc(const float* __restrict__ atom_table,
                           const float* __restrict__ vn0,
                           const int* __restrict__ x,
                           float* __restrict__ h) {
    int tid = blockIdx.x * blockDim.x + threadIdx.x;
    int n = tid >> 6, c = tid & 63;
    if (n >= NN) return;
    float acc = vn0[c];
    const int* xr = x + n * 9;
    #pragma unroll
    for (int f = 0; f < 9; ++f) acc += atom_table[(xr[f] + c_atom_off[f]) * HH + c];
    h[tid] = acc;
}

__global__ void k_vn_init(const float* __restrict__ vn0, float* __restrict__ vn) {
    int tid = blockIdx.x * blockDim.x + threadIdx.x;
    if (tid < GH) vn[tid] = vn0[tid & 63];
}

// combined bond-embedding table: ctab[c][lane], c = a0 + 5*a1 + 30*a2  (60 combos)
__global__ void k_ctab(const float* __restrict__ bond, float* __restrict__ ctab) {
    int c = blockIdx.x, lane = threadIdx.x;
    int a0 = c % 5, a1 = (c / 5) % 6, a2 = c / 30;
    ctab[c * 64 + lane] = bond[a0 * 64 + lane] + bond[(5 + a1) * 64 + lane]
                        + bond[(11 + a2) * 64 + lane];
}

// ---------------- CSR build ----------------

__global__ void k_count(const int* __restrict__ edge_index, int* __restrict__ cur) {
    int e = blockIdx.x * blockDim.x + threadIdx.x;
    if (e >= EE) return;
    atomicAdd(&cur[edge_index[EE + e]], 1);
}

__global__ void k_scan1(const int* __restrict__ cnt, int* __restrict__ rp, int* __restrict__ part) {
    __shared__ int s[256];
    int t = threadIdx.x, blk = blockIdx.x;
    int base = blk * 1024 + t * 4;
    int v0 = 0, v1 = 0, v2 = 0, v3 = 0;
    if (base + 3 < NN) {
        int4 q = *(const int4*)(cnt + base);
        v0 = q.x; v1 = q.y; v2 = q.z; v3 = q.w;
    } else {
        if (base + 0 < NN) v0 = cnt[base + 0];
        if (base + 1 < NN) v1 = cnt[base + 1];
        if (base + 2 < NN) v2 = cnt[base + 2];
        if (base + 3 < NN) v3 = cnt[base + 3];
    }
    int s4 = v0 + v1 + v2 + v3;
    s[t] = s4;
    __syncthreads();
    for (int off = 1; off < 256; off <<= 1) {
        int x = (t >= off) ? s[t - off] : 0;
        __syncthreads();
        s[t] += x;
        __syncthreads();
    }
    int excl = s[t] - s4;
    if (t == 255) part[blk] = s[255];
    if (base + 0 < NN) rp[base + 0] = excl;
    if (base + 1 < NN) rp[base + 1] = excl + v0;
    if (base + 2 < NN) rp[base + 2] = excl + v0 + v1;
    if (base + 3 < NN) rp[base + 3] = excl + v0 + v1 + v2;
}

__global__ void k_scan2(int* __restrict__ part) {
    __shared__ int s[128];
    int t = threadIdx.x;
    int v = (t < SCAN_BLKS) ? part[t] : 0;
    s[t] = v;
    __syncthreads();
    for (int off = 1; off < 128; off <<= 1) {
        int x = (t >= off) ? s[t - off] : 0;
        __syncthreads();
        s[t] += x;
        __syncthreads();
    }
    if (t < SCAN_BLKS) part[t] = s[t] - v;
}

__global__ void k_scan3(int* __restrict__ rp, const int* __restrict__ part) {
    int i = blockIdx.x * blockDim.x + threadIdx.x;
    if (i < NN) rp[i] += part[i >> 10];
    if (i == 0) rp[NN] = EE;
}

__global__ void k_fill(const int* __restrict__ edge_index, const int* __restrict__ edge_attr,
                       const int* __restrict__ rp, int* __restrict__ cur,
                       int2* __restrict__ edges) {
    int e = blockIdx.x * blockDim.x + threadIdx.x;
    if (e >= EE) return;
    int src = edge_index[e];
    int dst = edge_index[EE + e];
    int combo = edge_attr[e * 3] + 5 * edge_attr[e * 3 + 1] + 30 * edge_attr[e * 3 + 2];
    int slot = rp[dst] + atomicAdd(&cur[dst], 1);
    edges[slot] = make_int2(src, combo);
}

// ---------------- fused: aggregate + conv GEMM (+res) + BN stats of output ----------------
__global__ __launch_bounds__(512) void k_conv_fused(
        const float* __restrict__ gsrc, const float* res,
        const int* __restrict__ rp, const int2* __restrict__ edges,
        const float* __restrict__ ctab,
        const float* __restrict__ W, const float* __restrict__ bvec,
        float* __restrict__ out, float* __restrict__ stats) {
    __shared__ float sW[4096];
    __shared__ float sC[3840];
    __shared__ float sRed[2][8][64];
    for (int i = threadIdx.x; i < 4096; i += 512) sW[i] = W[i];
    for (int i = threadIdx.x; i < 3840; i += 512) sC[i] = ctab[i];
    __syncthreads();
    int lane = threadIdx.x & 63;
    int wv = threadIdx.x >> 6;
    int w = blockIdx.x * CONV_WPB + wv;
    float bias = bvec[lane];
    float psum = 0.f, psq = 0.f;
    int n0 = w * CONV_CHUNK;
    int n1 = min(n0 + CONV_CHUNK, NN);
    for (int n = n0; n < n1; ++n) {
        int beg = rp[n], end = rp[n + 1];
        float acc = (float)(end - beg) * EPS_GEN;
        int e = beg;
        for (; e + 2 <= end; e += 2) {
            int2 e0 = edges[e], e1 = edges[e + 1];
            float h0 = gsrc[(size_t)e0.x * 64 + lane];
            float h1 = gsrc[(size_t)e1.x * 64 + lane];
            float c0 = sC[e0.y * 64 + lane];
            float c1 = sC[e1.y * 64 + lane];
            acc += fmaxf(h0 + c0, 0.f) + fmaxf(h1 + c1, 0.f);
        }
        if (e < end) {
            int2 e0 = edges[e];
            acc += fmaxf(gsrc[(size_t)e0.x * 64 + lane] + sC[e0.y * 64 + lane], 0.f);
        }
        float va = gsrc[(size_t)n * 64 + lane] + acc;
        float r = bias;
        #pragma unroll
        for (int k = 0; k < 64; ++k)
            r = fmaf(__shfl(va, k, 64), sW[k * 64 + lane], r);
        if (res) r += res[(size_t)n * 64 + lane];
        out[(size_t)n * 64 + lane] = r;
        psum += r; psq = fmaf(r, r, psq);
    }
    sRed[0][wv][lane] = psum;
    sRed[1][wv][lane] = psq;
    __syncthreads();
    if (threadIdx.x < 64) {
        float s = 0.f, q = 0.f;
        #pragma unroll
        for (int i = 0; i < 8; ++i) { s += sRed[0][i][threadIdx.x]; q += sRed[1][i][threadIdx.x]; }
        atomicAdd(&stats[threadIdx.x], s);
        atomicAdd(&stats[64 + threadIdx.x], q);
    }
}

// ---------------- BN / pooling ----------------

// h2 = relu(bn(h)); vt[batch[n]] += h2[n], run-length aggregated; chunk=16 nodes/wave
__global__ void k_bn_relu_vt2(const float* __restrict__ h, const float* __restrict__ stats,
                              const float* __restrict__ gamma, const float* __restrict__ beta,
                              const int* __restrict__ batch,
                              float* __restrict__ h2, float* __restrict__ vt) {
    int lane = threadIdx.x & 63;
    int w = blockIdx.x * 4 + (threadIdx.x >> 6);
    int n0 = w * 16;
    if (n0 >= NN) return;
    int n1 = min(n0 + 16, NN);
    float mu = stats[lane] * (1.f / NN);
    float var = stats[64 + lane] * (1.f / NN) - mu * mu;
    float inv = rsqrtf(var + EPS_BN) * gamma[lane];
    float bet = beta[lane];
    float acc = 0.f;
    int gcur = batch[n0];
    for (int n = n0; n < n1; ++n) {
        float v = fmaxf((h[(size_t)n * 64 + lane] - mu) * inv + bet, 0.f);
        h2[(size_t)n * 64 + lane] = v;
        int g = batch[n];
        if (g != gcur) {
            atomicAdd(&vt[(size_t)gcur * 64 + lane], acc);
            acc = 0.f; gcur = g;
        }
        acc += v;
    }
    atomicAdd(&vt[(size_t)gcur * 64 + lane], acc);
}

// out[r] = (in[r] (+in2[r])) @ W + b, rows=512 fixed; fused BN-stats of out
__global__ void k_gemm_small_stats(const float* __restrict__ in, const float* in2,
                                   const float* __restrict__ W, const float* __restrict__ bvec,
                                   float* __restrict__ out, float* __restrict__ stats) {
    __shared__ float sW[4096];
    __shared__ float sRed[2][4][64];
    for (int i = threadIdx.x; i < 4096; i += 256) sW[i] = W[i];
    __syncthreads();
    int lane = threadIdx.x & 63, wv = threadIdx.x >> 6;
    int w = blockIdx.x * 4 + wv;          // 32 waves, 16 rows each
    float psum = 0.f, psq = 0.f;
    for (int r = w * 16; r < w * 16 + 16; ++r) {
        float va = in[r * 64 + lane];
        if (in2) va += in2[r * 64 + lane];
        float acc = bvec[lane];
        #pragma unroll
        for (int k = 0; k < 64; ++k)
            acc = fmaf(__shfl(va, k, 64), sW[k * 64 + lane], acc);
        out[r * 64 + lane] = acc;
        psum += acc; psq = fmaf(acc, acc, psq);
    }
    sRed[0][wv][lane] = psum;
    sRed[1][wv][lane] = psq;
    __syncthreads();
    if (threadIdx.x < 64) {
        float s = 0.f, q = 0.f;
        #pragma unroll
        for (int i = 0; i < 4; ++i) { s += sRed[0][i][threadIdx.x]; q += sRed[1][i][threadIdx.x]; }
        atomicAdd(&stats[threadIdx.x], s);
        atomicAdd(&stats[64 + threadIdx.x], q);
    }
}

__global__ void k_bn_act(const float* __restrict__ in, const float* __restrict__ stats,
                         const float* __restrict__ gamma, const float* __restrict__ beta,
                         int rows, float rows_inv, int do_relu, float* __restrict__ out) {
    int tid = blockIdx.x * blockDim.x + threadIdx.x;
    if (tid >= rows * HH) return;
    int c = tid & 63;
    float mu = stats[c] * rows_inv;
    float var = stats[64 + c] * rows_inv - mu * mu;
    float inv = rsqrtf(var + EPS_BN);
    float v = (in[tid] - mu) * inv * gamma[c] + beta[c];
    if (do_relu) v = fmaxf(v, 0.f);
    out[tid] = v;
}

__global__ void k_add_vn(float* __restrict__ h2, const float* __restrict__ vn,
                         const int* __restrict__ batch) {
    int tid = blockIdx.x * blockDim.x + threadIdx.x;
    int n = tid >> 6, c = tid & 63;
    if (n >= NN) return;
    h2[tid] += vn[batch[n] * HH + c];
}

// final BN + mean-pool, run-length aggregated; chunk=32
__global__ void k_pool2(const float* __restrict__ h, const float* __restrict__ stats,
                        const float* __restrict__ gamma, const float* __restrict__ beta,
                        const int* __restrict__ batch,
                        float* __restrict__ out, float* __restrict__ cnt) {
    int lane = threadIdx.x & 63;
    int w = blockIdx.x * 4 + (threadIdx.x >> 6);
    int n0 = w * 32;
    if (n0 >= NN) return;
    int n1 = min(n0 + 32, NN);
    float mu = stats[lane] * (1.f / NN);
    float var = stats[64 + lane] * (1.f / NN) - mu * mu;
    float inv = rsqrtf(var + EPS_BN) * gamma[lane];
    float bet = beta[lane];
    float acc = 0.f;
    int run = 0;
    int gcur = batch[n0];
    for (int n = n0; n < n1; ++n) {
        float v = (h[(size_t)n * 64 + lane] - mu) * inv + bet;
        int g = batch[n];
        if (g != gcur) {
            atomicAdd(&out[(size_t)gcur * 64 + lane], acc);
            if (lane == 0) atomicAdd(&cnt[gcur], (float)run);
            acc = 0.f; run = 0; gcur = g;
        }
        acc += v; run++;
    }
    atomicAdd(&out[(size_t)gcur * 64 + lane], acc);
    if (lane == 0) atomicAdd(&cnt[gcur], (float)run);
}

__global__ void k_div(float* __restrict__ out, const float* __restrict__ cnt) {
    int tid = blockIdx.x * blockDim.x + threadIdx.x;
    if (tid >= GH) return;
    out[tid] /= fmaxf(cnt[tid >> 6], 1.0f);
}

extern "C" void kernel_launch(void* const* d_in, const int* in_sizes, int n_in,
                              void* d_out, int out_size, void* d_ws, size_t ws_size,
                              hipStream_t stream) {
    const float* atom_table = (const float*)d_in[0];
    const float* bond_table = (const float*)d_in[1];
    const float* vn0   = (const float*)d_in[2];
    const float* gcn_W = (const float*)d_in[3];
    const float* gcn_b = (const float*)d_in[4];
    const float* ng    = (const float*)d_in[5];
    const float* nb    = (const float*)d_in[6];
    const float* vn_W1 = (const float*)d_in[7];
    const float* vn_b1 = (const float*)d_in[8];
    const float* vn_g1 = (const float*)d_in[9];
    const float* vn_be1= (const float*)d_in[10];
    const float* vn_W2 = (const float*)d_in[11];
    const float* vn_b2 = (const float*)d_in[12];
    const float* vn_g2 = (const float*)d_in[13];
    const float* vn_be2= (const float*)d_in[14];
    const int* x          = (const int*)d_in[15];
    const int* edge_index = (const int*)d_in[16];
    const int* edge_attr  = (const int*)d_in[17];
    const int* batch      = (const int*)d_in[18];

    float* ws = (float*)d_ws;
    float* hA  = ws;                     // NH (encoder out / h2)
    float* hB  = ws + (size_t)NH;        // NH (running h)
    float* h2  = hA;
    float* vn  = ws + (size_t)2 * NH;    // GH
    float* vt  = vn + GH;                // GH
    float* t   = vt + GH;                // GH
    float* z   = t + GH;                 // GH
    float* statsAll = z + GH;            // 19*128 (7 conv + 6 vn1 + 6 vn2)
    float* cnt    = statsAll + 19 * 128; // GG
    float* ctab   = cnt + GG;            // 60*64
    int*   rp     = (int*)(ctab + 60 * 64);  // NN+1
    int*   cur    = rp + (NN + 1);           // NN
    int*   part   = cur + NN;                // 128
    int*   pad    = part + 128;              // +1 align to 8B for int2
    int2*  edges  = (int2*)((((uintptr_t)pad) + 7) & ~(uintptr_t)7);

    float* convStats = statsAll;                 // [7][128]
    float* vn1Stats  = statsAll + 7 * 128;       // [6][128]
    float* vn2Stats  = statsAll + 13 * 128;      // [6][128]

    const int blkN = NH / 256;               // 25000
    const int blkG = (GH + 255) / 256;       // 128
    const int blkE = (EE + 255) / 256;       // 3907
    const int blkRL = ((NN + 15) / 16 + 3) / 4;   // bn_relu_vt2, chunk 16
    const int blkPL = ((NN + 31) / 32 + 3) / 4;   // pool2, chunk 32
    float* outp = (float*)d_out;

    k_atom_enc<<<blkN, 256, 0, stream>>>(atom_table, vn0, x, hA);
    k_vn_init<<<blkG, 256, 0, stream>>>(vn0, vn);
    k_ctab<<<60, 64, 0, stream>>>(bond_table, ctab);
    hipMemsetAsync(statsAll, 0, 19 * 128 * 4, stream);

    // ---- CSR build ----
    hipMemsetAsync(cur, 0, (size_t)NN * 4, stream);
    k_count<<<blkE, 256, 0, stream>>>(edge_index, cur);
    k_scan1<<<SCAN_BLKS, 256, 0, stream>>>(cur, rp, part);
    k_scan2<<<1, 128, 0, stream>>>(part);
    k_scan3<<<(NN + 255) / 256, 256, 0, stream>>>(rp, part);
    hipMemsetAsync(cur, 0, (size_t)NN * 4, stream);
    k_fill<<<blkE, 256, 0, stream>>>(edge_index, edge_attr, rp, cur, edges);

    // ---- layer 0 ----
    k_conv_fused<<<CONV_BLOCKS, 512, 0, stream>>>(hA, nullptr, rp, edges, ctab,
                                                  gcn_W, gcn_b, hB, convStats);

    for (int l = 1; l < LL; ++l) {
        hipMemsetAsync(vt, 0, (size_t)GH * 4, stream);
        k_bn_relu_vt2<<<blkRL, 256, 0, stream>>>(hB, convStats + (size_t)(l - 1) * 128,
                                                 ng + (size_t)(l - 1) * HH,
                                                 nb + (size_t)(l - 1) * HH, batch, h2, vt);
        // VN MLP: vn = relu(bn(relu(bn((vt+vn)@W1+b1)) @ W2 + b2))
        k_gemm_small_stats<<<8, 256, 0, stream>>>(vt, vn, vn_W1 + (size_t)(l - 1) * 4096,
                                                  vn_b1 + (size_t)(l - 1) * HH, t,
                                                  vn1Stats + (size_t)(l - 1) * 128);
        k_bn_act<<<blkG, 256, 0, stream>>>(t, vn1Stats + (size_t)(l - 1) * 128,
                                           vn_g1 + (size_t)(l - 1) * HH,
                                           vn_be1 + (size_t)(l - 1) * HH, GG, 1.f / GG, 1, z);
        k_gemm_small_stats<<<8, 256, 0, stream>>>(z, nullptr, vn_W2 + (size_t)(l - 1) * 4096,
                                                  vn_b2 + (size_t)(l - 1) * HH, t,
                                                  vn2Stats + (size_t)(l - 1) * 128);
        k_bn_act<<<blkG, 256, 0, stream>>>(t, vn2Stats + (size_t)(l - 1) * 128,
                                           vn_g2 + (size_t)(l - 1) * HH,
                                           vn_be2 + (size_t)(l - 1) * HH, GG, 1.f / GG, 1, vn);

        k_add_vn<<<blkN, 256, 0, stream>>>(h2, vn, batch);

        k_conv_fused<<<CONV_BLOCKS, 512, 0, stream>>>(h2, hB, rp, edges, ctab,
                                                      gcn_W + (size_t)l * 4096,
                                                      gcn_b + (size_t)l * HH, hB,
                                                      convStats + (size_t)l * 128);
    }

    // ---- final BN + mean pool (stats from last conv) ----
    hipMemsetAsync(outp, 0, (size_t)GH * 4, stream);
    hipMemsetAsync(cnt, 0, (size_t)GG * 4, stream);
    k_pool2<<<blkPL, 256, 0, stream>>>(hB, convStats + 6 * 128,
                                       ng + (size_t)6 * HH, nb + (size_t)6 * HH,
                                       batch, outp, cnt);
    k_div<<<blkG, 256, 0, stream>>>(outp, cnt);
}

// Round 4
// 2092.982 us; speedup vs baseline: 1.5735x; 1.0335x over previous
//
#include <hip/hip_runtime.h>
#include <hip/hip_bf16.h>

#define NN 100000
#define EE 1000000
#define GG 512
#define HH 64
#define LL 7
#define NH (NN*HH)
#define GH (GG*HH)
#define EPS_GEN 1e-7f
#define EPS_BN 1e-5f
#define SCAN_BLKS 98   // ceil(NN/1024)

#define SLOTS 64
#define CONV_BLOCKS 3125
#define CONV_WPB 4
#define CONV_CHUNK 8   // 3125*4*8 == 100000 exactly

__device__ __constant__ int c_atom_off[9] = {0,119,124,136,148,158,164,170,172};

__global__ void k_atom_enc(const float* __restrict__ atom_table,
                           const float* __restrict__ vn0,
                           const int* __restrict__ x,
                           float* __restrict__ h) {
    int tid = blockIdx.x * blockDim.x + threadIdx.x;
    int n = tid >> 6, c = tid & 63;
    if (n >= NN) return;
    float acc = vn0[c];
    const int* xr = x + n * 9;
    #pragma unroll
    for (int f = 0; f < 9; ++f) acc += atom_table[(xr[f] + c_atom_off[f]) * HH + c];
    h[tid] = acc;
}

// combined bond-embedding table: ctab[c][lane], c = a0 + 5*a1 + 30*a2  (60 combos)
__global__ void k_ctab(const float* __restrict__ bond, float* __restrict__ ctab) {
    int c = blockIdx.x, lane = threadIdx.x;
    int a0 = c % 5, a1 = (c / 5) % 6, a2 = c / 30;
    ctab[c * 64 + lane] = bond[a0 * 64 + lane] + bond[(5 + a1) * 64 + lane]
                        + bond[(11 + a2) * 64 + lane];
}

// ---------------- CSR build ----------------

__global__ void k_count(const int* __restrict__ edge_index, int* __restrict__ cur) {
    int e = blockIdx.x * blockDim.x + threadIdx.x;
    if (e >= EE) return;
    atomicAdd(&cur[edge_index[EE + e]], 1);
}

__global__ void k_scan1(const int* __restrict__ cnt, int* __restrict__ rp, int* __restrict__ part) {
    __shared__ int s[256];
    int t = threadIdx.x, blk = blockIdx.x;
    int base = blk * 1024 + t * 4;
    int v0 = 0, v1 = 0, v2 = 0, v3 = 0;
    if (base + 3 < NN) {
        int4 q = *(const int4*)(cnt + base);
        v0 = q.x; v1 = q.y; v2 = q.z; v3 = q.w;
    } else {
        if (base + 0 < NN) v0 = cnt[base + 0];
        if (base + 1 < NN) v1 = cnt[base + 1];
        if (base + 2 < NN) v2 = cnt[base + 2];
        if (base + 3 < NN) v3 = cnt[base + 3];
    }
    int s4 = v0 + v1 + v2 + v3;
    s[t] = s4;
    __syncthreads();
    for (int off = 1; off < 256; off <<= 1) {
        int x = (t >= off) ? s[t - off] : 0;
        __syncthreads();
        s[t] += x;
        __syncthreads();
    }
    int excl = s[t] - s4;
    if (t == 255) part[blk] = s[255];
    if (base + 0 < NN) rp[base + 0] = excl;
    if (base + 1 < NN) rp[base + 1] = excl + v0;
    if (base + 2 < NN) rp[base + 2] = excl + v0 + v1;
    if (base + 3 < NN) rp[base + 3] = excl + v0 + v1 + v2;
}

__global__ void k_scan2(int* __restrict__ part) {
    __shared__ int s[128];
    int t = threadIdx.x;
    int v = (t < SCAN_BLKS) ? part[t] : 0;
    s[t] = v;
    __syncthreads();
    for (int off = 1; off < 128; off <<= 1) {
        int x = (t >= off) ? s[t - off] : 0;
        __syncthreads();
        s[t] += x;
        __syncthreads();
    }
    if (t < SCAN_BLKS) part[t] = s[t] - v;
}

__global__ void k_scan3(int* __restrict__ rp, const int* __restrict__ part) {
    int i = blockIdx.x * blockDim.x + threadIdx.x;
    if (i < NN) rp[i] += part[i >> 10];
    if (i == 0) rp[NN] = EE;
}

__global__ void k_fill(const int* __restrict__ edge_index, const int* __restrict__ edge_attr,
                       const int* __restrict__ rp, int* __restrict__ cur,
                       int2* __restrict__ edges) {
    int e = blockIdx.x * blockDim.x + threadIdx.x;
    if (e >= EE) return;
    int src = edge_index[e];
    int dst = edge_index[EE + e];
    int combo = edge_attr[e * 3] + 5 * edge_attr[e * 3 + 1] + 30 * edge_attr[e * 3 + 2];
    int slot = rp[dst] + atomicAdd(&cur[dst], 1);
    edges[slot] = make_int2(src, combo);
}

// ---------------- fused: aggregate + conv GEMM (+res) + BN stats partials ----------------
// W held in 64 VGPRs per lane; edge records loaded coalesced + shfl-broadcast; 4x gather MLP.
__global__ __launch_bounds__(256, 4) void k_conv_fused(
        const float* __restrict__ gsrc, const float* res,
        const int* __restrict__ rp, const int2* __restrict__ edges,
        const float* __restrict__ ctab,
        const float* __restrict__ W, const float* __restrict__ bvec,
        float* __restrict__ out, float* __restrict__ statsPart) {
    __shared__ float sRed[2][CONV_WPB][64];
    int lane = threadIdx.x & 63;
    int wv = threadIdx.x >> 6;
    float wreg[64];
    #pragma unroll
    for (int k = 0; k < 64; ++k) wreg[k] = W[k * 64 + lane];
    float bias = bvec[lane];
    int w = blockIdx.x * CONV_WPB + wv;
    int n0 = w * CONV_CHUNK;
    int n1 = min(n0 + CONV_CHUNK, NN);
    float psum = 0.f, psq = 0.f;
    for (int n = n0; n < n1; ++n) {
        int beg = rp[n], end = rp[n + 1];
        int deg = end - beg;
        float acc = (float)deg * EPS_GEN;
        for (int base = 0; base < deg; base += 64) {
            int cnt = min(64, deg - base);
            int2 me = make_int2(0, 0);
            if (lane < cnt) me = edges[beg + base + lane];
            int j = 0;
            for (; j + 4 <= cnt; j += 4) {
                int s0 = __shfl(me.x, j, 64),     c0 = __shfl(me.y, j, 64);
                int s1 = __shfl(me.x, j + 1, 64), c1 = __shfl(me.y, j + 1, 64);
                int s2 = __shfl(me.x, j + 2, 64), c2 = __shfl(me.y, j + 2, 64);
                int s3 = __shfl(me.x, j + 3, 64), c3 = __shfl(me.y, j + 3, 64);
                float h0 = gsrc[(size_t)s0 * 64 + lane], t0 = ctab[c0 * 64 + lane];
                float h1 = gsrc[(size_t)s1 * 64 + lane], t1 = ctab[c1 * 64 + lane];
                float h2 = gsrc[(size_t)s2 * 64 + lane], t2 = ctab[c2 * 64 + lane];
                float h3 = gsrc[(size_t)s3 * 64 + lane], t3 = ctab[c3 * 64 + lane];
                acc += fmaxf(h0 + t0, 0.f) + fmaxf(h1 + t1, 0.f)
                     + fmaxf(h2 + t2, 0.f) + fmaxf(h3 + t3, 0.f);
            }
            for (; j < cnt; ++j) {
                int s0 = __shfl(me.x, j, 64), c0 = __shfl(me.y, j, 64);
                acc += fmaxf(gsrc[(size_t)s0 * 64 + lane] + ctab[c0 * 64 + lane], 0.f);
            }
        }
        float va = gsrc[(size_t)n * 64 + lane] + acc;
        float r = bias;
        #pragma unroll
        for (int k = 0; k < 64; ++k)
            r = fmaf(__shfl(va, k, 64), wreg[k], r);
        if (res) r += res[(size_t)n * 64 + lane];
        out[(size_t)n * 64 + lane] = r;
        psum += r; psq = fmaf(r, r, psq);
    }
    sRed[0][wv][lane] = psum;
    sRed[1][wv][lane] = psq;
    __syncthreads();
    if (threadIdx.x < 64) {
        float s = 0.f, q = 0.f;
        #pragma unroll
        for (int i = 0; i < CONV_WPB; ++i) { s += sRed[0][i][threadIdx.x]; q += sRed[1][i][threadIdx.x]; }
        float* sp = statsPart + (blockIdx.x & (SLOTS - 1)) * 128;
        atomicAdd(&sp[threadIdx.x], s);
        atomicAdd(&sp[64 + threadIdx.x], q);
    }
}

// ---------------- BN / pooling ----------------

__device__ inline void load_stats64(const float* __restrict__ sp, int lane, float& s, float& q) {
    s = 0.f; q = 0.f;
    for (int i = 0; i < SLOTS; ++i) { s += sp[i * 128 + lane]; q += sp[i * 128 + 64 + lane]; }
}

// h2 = relu(bn(h)); vt[batch[n]] += h2[n], run-length aggregated; chunk=16 nodes/wave
__global__ void k_bn_relu_vt2(const float* __restrict__ h, const float* __restrict__ statsPart,
                              const float* __restrict__ gamma, const float* __restrict__ beta,
                              const int* __restrict__ batch,
                              float* __restrict__ h2, float* __restrict__ vt) {
    int lane = threadIdx.x & 63;
    int w = blockIdx.x * 4 + (threadIdx.x >> 6);
    int n0 = w * 16;
    if (n0 >= NN) return;
    int n1 = min(n0 + 16, NN);
    float ssum, ssq;
    load_stats64(statsPart, lane, ssum, ssq);
    float mu = ssum * (1.f / NN);
    float var = ssq * (1.f / NN) - mu * mu;
    float inv = rsqrtf(var + EPS_BN) * gamma[lane];
    float bet = beta[lane];
    float acc = 0.f;
    int gcur = batch[n0];
    for (int n = n0; n < n1; ++n) {
        float v = fmaxf((h[(size_t)n * 64 + lane] - mu) * inv + bet, 0.f);
        h2[(size_t)n * 64 + lane] = v;
        int g = batch[n];
        if (g != gcur) {
            atomicAdd(&vt[(size_t)gcur * 64 + lane], acc);
            acc = 0.f; gcur = g;
        }
        acc += v;
    }
    atomicAdd(&vt[(size_t)gcur * 64 + lane], acc);
}

// VN GEMM over 512 rows: out = (bnrelu?(in) + addterm) @ W + b; writes out-stats.
// in_stats!=null: in := relu((in-mu)*inv*g+be). add!=null: add_stats!=null ? bnrelu(add[r]) : add[lane].
__global__ void k_vn_gemm(const float* __restrict__ in, const float* in_stats,
                          const float* in_g, const float* in_be,
                          const float* add, const float* add_stats,
                          const float* add_g, const float* add_be,
                          const float* __restrict__ W, const float* __restrict__ bvec,
                          float* __restrict__ out, float* __restrict__ out_stats) {
    __shared__ float sW[4096];
    __shared__ float sRed[2][4][64];
    for (int i = threadIdx.x; i < 4096; i += 256) sW[i] = W[i];
    __syncthreads();
    int lane = threadIdx.x & 63, wv = threadIdx.x >> 6;
    int w = blockIdx.x * 4 + wv;          // 32 waves, 16 rows each
    float imu = 0.f, iinv = 0.f, ibe = 0.f;
    if (in_stats) {
        float mu = in_stats[lane] * (1.f / GG);
        float var = in_stats[64 + lane] * (1.f / GG) - mu * mu;
        imu = mu; iinv = rsqrtf(var + EPS_BN) * in_g[lane]; ibe = in_be[lane];
    }
    float amu = 0.f, ainv = 0.f, abe = 0.f;
    if (add && add_stats) {
        float mu = add_stats[lane] * (1.f / GG);
        float var = add_stats[64 + lane] * (1.f / GG) - mu * mu;
        amu = mu; ainv = rsqrtf(var + EPS_BN) * add_g[lane]; abe = add_be[lane];
    }
    float psum = 0.f, psq = 0.f;
    for (int r = w * 16; r < w * 16 + 16; ++r) {
        float va = in[r * 64 + lane];
        if (in_stats) va = fmaxf((va - imu) * iinv + ibe, 0.f);
        if (add) {
            float av;
            if (add_stats) av = fmaxf((add[r * 64 + lane] - amu) * ainv + abe, 0.f);
            else av = add[lane];
            va += av;
        }
        float acc = bvec[lane];
        #pragma unroll
        for (int k = 0; k < 64; ++k)
            acc = fmaf(__shfl(va, k, 64), sW[k * 64 + lane], acc);
        out[r * 64 + lane] = acc;
        psum += acc; psq = fmaf(acc, acc, psq);
    }
    sRed[0][wv][lane] = psum;
    sRed[1][wv][lane] = psq;
    __syncthreads();
    if (threadIdx.x < 64) {
        float s = 0.f, q = 0.f;
        #pragma unroll
        for (int i = 0; i < 4; ++i) { s += sRed[0][i][threadIdx.x]; q += sRed[1][i][threadIdx.x]; }
        atomicAdd(&out_stats[threadIdx.x], s);
        atomicAdd(&out_stats[64 + threadIdx.x], q);
    }
}

// h2[n] += bnrelu(t2)[batch[n]]  (vn materialization avoided)
__global__ void k_add_vn2(float* __restrict__ h2, const float* __restrict__ t2,
                          const float* __restrict__ stats2,
                          const float* __restrict__ g2, const float* __restrict__ be2,
                          const int* __restrict__ batch) {
    int tid = blockIdx.x * blockDim.x + threadIdx.x;
    int n = tid >> 6, c = tid & 63;
    if (n >= NN) return;
    float mu = stats2[c] * (1.f / GG);
    float var = stats2[64 + c] * (1.f / GG) - mu * mu;
    float inv = rsqrtf(var + EPS_BN) * g2[c];
    float v = fmaxf((t2[(size_t)batch[n] * 64 + c] - mu) * inv + be2[c], 0.f);
    h2[tid] += v;
}

// final BN + mean-pool, run-length aggregated; chunk=32
__global__ void k_pool2(const float* __restrict__ h, const float* __restrict__ statsPart,
                        const float* __restrict__ gamma, const float* __restrict__ beta,
                        const int* __restrict__ batch,
                        float* __restrict__ out, float* __restrict__ cnt) {
    int lane = threadIdx.x & 63;
    int w = blockIdx.x * 4 + (threadIdx.x >> 6);
    int n0 = w * 32;
    if (n0 >= NN) return;
    int n1 = min(n0 + 32, NN);
    float ssum, ssq;
    load_stats64(statsPart, lane, ssum, ssq);
    float mu = ssum * (1.f / NN);
    float var = ssq * (1.f / NN) - mu * mu;
    float inv = rsqrtf(var + EPS_BN) * gamma[lane];
    float bet = beta[lane];
    float acc = 0.f;
    int run = 0;
    int gcur = batch[n0];
    for (int n = n0; n < n1; ++n) {
        float v = (h[(size_t)n * 64 + lane] - mu) * inv + bet;
        int g = batch[n];
        if (g != gcur) {
            atomicAdd(&out[(size_t)gcur * 64 + lane], acc);
            if (lane == 0) atomicAdd(&cnt[gcur], (float)run);
            acc = 0.f; run = 0; gcur = g;
        }
        acc += v; run++;
    }
    atomicAdd(&out[(size_t)gcur * 64 + lane], acc);
    if (lane == 0) atomicAdd(&cnt[gcur], (float)run);
}

__global__ void k_div(float* __restrict__ out, const float* __restrict__ cnt) {
    int tid = blockIdx.x * blockDim.x + threadIdx.x;
    if (tid >= GH) return;
    out[tid] /= fmaxf(cnt[tid >> 6], 1.0f);
}

extern "C" void kernel_launch(void* const* d_in, const int* in_sizes, int n_in,
                              void* d_out, int out_size, void* d_ws, size_t ws_size,
                              hipStream_t stream) {
    const float* atom_table = (const float*)d_in[0];
    const float* bond_table = (const float*)d_in[1];
    const float* vn0   = (const float*)d_in[2];
    const float* gcn_W = (const float*)d_in[3];
    const float* gcn_b = (const float*)d_in[4];
    const float* ng    = (const float*)d_in[5];
    const float* nb    = (const float*)d_in[6];
    const float* vn_W1 = (const float*)d_in[7];
    const float* vn_b1 = (const float*)d_in[8];
    const float* vn_g1 = (const float*)d_in[9];
    const float* vn_be1= (const float*)d_in[10];
    const float* vn_W2 = (const float*)d_in[11];
    const float* vn_b2 = (const float*)d_in[12];
    const float* vn_g2 = (const float*)d_in[13];
    const float* vn_be2= (const float*)d_in[14];
    const int* x          = (const int*)d_in[15];
    const int* edge_index = (const int*)d_in[16];
    const int* edge_attr  = (const int*)d_in[17];
    const int* batch      = (const int*)d_in[18];

    float* ws = (float*)d_ws;
    float* hA  = ws;                     // NH (encoder out / h2)
    float* hB  = ws + (size_t)NH;        // NH (running h)
    float* h2  = hA;
    float* vt  = ws + (size_t)2 * NH;    // GH
    float* t1  = vt + GH;                // GH
    float* t2  = t1 + GH;                // GH
    float* convStatsP = t2 + GH;             // 7 * SLOTS * 128
    float* vn1Stats   = convStatsP + 7 * SLOTS * 128;  // 6*128
    float* vn2Stats   = vn1Stats + 6 * 128;            // 6*128
    float* cnt    = vn2Stats + 6 * 128;  // GG
    float* ctab   = cnt + GG;            // 60*64
    int*   rp     = (int*)(ctab + 60 * 64);  // NN+1
    int*   cur    = rp + (NN + 1);           // NN
    int*   part   = cur + NN;                // 128
    int*   pad    = part + 128;
    int2*  edges  = (int2*)((((uintptr_t)pad) + 7) & ~(uintptr_t)7);

    const int blkN = NH / 256;               // 25000
    const int blkG = (GH + 255) / 256;       // 128
    const int blkE = (EE + 255) / 256;       // 3907
    const int blkRL = ((NN + 15) / 16 + 3) / 4;
    const int blkPL = ((NN + 31) / 32 + 3) / 4;
    float* outp = (float*)d_out;

    k_atom_enc<<<blkN, 256, 0, stream>>>(atom_table, vn0, x, hA);
    k_ctab<<<60, 64, 0, stream>>>(bond_table, ctab);
    hipMemsetAsync(convStatsP, 0, (7 * SLOTS * 128 + 12 * 128) * 4, stream);

    // ---- CSR build ----
    hipMemsetAsync(cur, 0, (size_t)NN * 4, stream);
    k_count<<<blkE, 256, 0, stream>>>(edge_index, cur);
    k_scan1<<<SCAN_BLKS, 256, 0, stream>>>(cur, rp, part);
    k_scan2<<<1, 128, 0, stream>>>(part);
    k_scan3<<<(NN + 255) / 256, 256, 0, stream>>>(rp, part);
    hipMemsetAsync(cur, 0, (size_t)NN * 4, stream);
    k_fill<<<blkE, 256, 0, stream>>>(edge_index, edge_attr, rp, cur, edges);

    // ---- layer 0 ----
    k_conv_fused<<<CONV_BLOCKS, 256, 0, stream>>>(hA, nullptr, rp, edges, ctab,
                                                  gcn_W, gcn_b, hB, convStatsP);

    for (int l = 1; l < LL; ++l) {
        hipMemsetAsync(vt, 0, (size_t)GH * 4, stream);
        k_bn_relu_vt2<<<blkRL, 256, 0, stream>>>(hB, convStatsP + (size_t)(l - 1) * SLOTS * 128,
                                                 ng + (size_t)(l - 1) * HH,
                                                 nb + (size_t)(l - 1) * HH, batch, h2, vt);
        // t1 = (vt + vn_prev) @ W1 + b1 ; vn_prev = l==1 ? vn0 : bnrelu(t2, stats2[l-2])
        if (l == 1)
            k_vn_gemm<<<8, 256, 0, stream>>>(vt, nullptr, nullptr, nullptr,
                                             vn0, nullptr, nullptr, nullptr,
                                             vn_W1, vn_b1, t1, vn1Stats);
        else
            k_vn_gemm<<<8, 256, 0, stream>>>(vt, nullptr, nullptr, nullptr,
                                             t2, vn2Stats + (size_t)(l - 2) * 128,
                                             vn_g2 + (size_t)(l - 2) * HH,
                                             vn_be2 + (size_t)(l - 2) * HH,
                                             vn_W1 + (size_t)(l - 1) * 4096,
                                             vn_b1 + (size_t)(l - 1) * HH, t1,
                                             vn1Stats + (size_t)(l - 1) * 128);
        // t2 = bnrelu(t1) @ W2 + b2
        k_vn_gemm<<<8, 256, 0, stream>>>(t1, vn1Stats + (size_t)(l - 1) * 128,
                                         vn_g1 + (size_t)(l - 1) * HH,
                                         vn_be1 + (size_t)(l - 1) * HH,
                                         nullptr, nullptr, nullptr, nullptr,
                                         vn_W2 + (size_t)(l - 1) * 4096,
                                         vn_b2 + (size_t)(l - 1) * HH, t2,
                                         vn2Stats + (size_t)(l - 1) * 128);
        // h2 += bnrelu(t2)[batch]
        k_add_vn2<<<blkN, 256, 0, stream>>>(h2, t2, vn2Stats + (size_t)(l - 1) * 128,
                                            vn_g2 + (size_t)(l - 1) * HH,
                                            vn_be2 + (size_t)(l - 1) * HH, batch);

        k_conv_fused<<<CONV_BLOCKS, 256, 0, stream>>>(h2, hB, rp, edges, ctab,
                                                      gcn_W + (size_t)l * 4096,
                                                      gcn_b + (size_t)l * HH, hB,
                                                      convStatsP + (size_t)l * SLOTS * 128);
    }

    // ---- final BN + mean pool ----
    hipMemsetAsync(outp, 0, (size_t)GH * 4, stream);
    hipMemsetAsync(cnt, 0, (size_t)GG * 4, stream);
    k_pool2<<<blkPL, 256, 0, stream>>>(hB, convStatsP + (size_t)6 * SLOTS * 128,
                                       ng + (size_t)6 * HH, nb + (size_t)6 * HH,
                                       batch, outp, cnt);
    k_div<<<blkG, 256, 0, stream>>>(outp, cnt);
}

// Round 5
// 1971.032 us; speedup vs baseline: 1.6709x; 1.0619x over previous
//
#include <hip/hip_runtime.h>
#include <hip/hip_bf16.h>

#define NN 100000
#define EE 1000000
#define GG 512
#define HH 64
#define LL 7
#define NH (NN*HH)
#define GH (GG*HH)
#define EPS_GEN 1e-7f
#define EPS_BN 1e-5f
#define SCAN_BLKS 98   // ceil(NN/1024)

#define SLOTS 64
#define CONV_BLOCKS 6250
#define CONV_WPB 4
#define CONV_CHUNK 4   // 6250*4*4 == 100000 exactly

__device__ __constant__ int c_atom_off[9] = {0,119,124,136,148,158,164,170,172};

__global__ void k_atom_enc(const float* __restrict__ atom_table,
                           const float* __restrict__ vn0,
                           const int* __restrict__ x,
                           float* __restrict__ h) {
    int tid = blockIdx.x * blockDim.x + threadIdx.x;
    int n = tid >> 6, c = tid & 63;
    if (n >= NN) return;
    float acc = vn0[c];
    const int* xr = x + n * 9;
    #pragma unroll
    for (int f = 0; f < 9; ++f) acc += atom_table[(xr[f] + c_atom_off[f]) * HH + c];
    h[tid] = acc;
}

// combined bond-embedding table: ctab[c][lane], c = a0 + 5*a1 + 30*a2  (60 combos)
__global__ void k_ctab(const float* __restrict__ bond, float* __restrict__ ctab) {
    int c = blockIdx.x, lane = threadIdx.x;
    int a0 = c % 5, a1 = (c / 5) % 6, a2 = c / 30;
    ctab[c * 64 + lane] = bond[a0 * 64 + lane] + bond[(5 + a1) * 64 + lane]
                        + bond[(11 + a2) * 64 + lane];
}

// ---------------- CSR build ----------------

__global__ void k_count(const int* __restrict__ edge_index, int* __restrict__ cur) {
    int e = blockIdx.x * blockDim.x + threadIdx.x;
    if (e >= EE) return;
    atomicAdd(&cur[edge_index[EE + e]], 1);
}

__global__ void k_scan1(const int* __restrict__ cnt, int* __restrict__ rp, int* __restrict__ part) {
    __shared__ int s[256];
    int t = threadIdx.x, blk = blockIdx.x;
    int base = blk * 1024 + t * 4;
    int v0 = 0, v1 = 0, v2 = 0, v3 = 0;
    if (base + 3 < NN) {
        int4 q = *(const int4*)(cnt + base);
        v0 = q.x; v1 = q.y; v2 = q.z; v3 = q.w;
    } else {
        if (base + 0 < NN) v0 = cnt[base + 0];
        if (base + 1 < NN) v1 = cnt[base + 1];
        if (base + 2 < NN) v2 = cnt[base + 2];
        if (base + 3 < NN) v3 = cnt[base + 3];
    }
    int s4 = v0 + v1 + v2 + v3;
    s[t] = s4;
    __syncthreads();
    for (int off = 1; off < 256; off <<= 1) {
        int x = (t >= off) ? s[t - off] : 0;
        __syncthreads();
        s[t] += x;
        __syncthreads();
    }
    int excl = s[t] - s4;
    if (t == 255) part[blk] = s[255];
    if (base + 0 < NN) rp[base + 0] = excl;
    if (base + 1 < NN) rp[base + 1] = excl + v0;
    if (base + 2 < NN) rp[base + 2] = excl + v0 + v1;
    if (base + 3 < NN) rp[base + 3] = excl + v0 + v1 + v2;
}

__global__ void k_scan2(int* __restrict__ part) {
    __shared__ int s[128];
    int t = threadIdx.x;
    int v = (t < SCAN_BLKS) ? part[t] : 0;
    s[t] = v;
    __syncthreads();
    for (int off = 1; off < 128; off <<= 1) {
        int x = (t >= off) ? s[t - off] : 0;
        __syncthreads();
        s[t] += x;
        __syncthreads();
    }
    if (t < SCAN_BLKS) part[t] = s[t] - v;
}

__global__ void k_scan3(int* __restrict__ rp, const int* __restrict__ part) {
    int i = blockIdx.x * blockDim.x + threadIdx.x;
    if (i < NN) rp[i] += part[i >> 10];
    if (i == 0) rp[NN] = EE;
}

__global__ void k_fill(const int* __restrict__ edge_index, const int* __restrict__ edge_attr,
                       const int* __restrict__ rp, int* __restrict__ cur,
                       int2* __restrict__ edges) {
    int e = blockIdx.x * blockDim.x + threadIdx.x;
    if (e >= EE) return;
    int src = edge_index[e];
    int dst = edge_index[EE + e];
    int combo = edge_attr[e * 3] + 5 * edge_attr[e * 3 + 1] + 30 * edge_attr[e * 3 + 2];
    int slot = rp[dst] + atomicAdd(&cur[dst], 1);
    edges[slot] = make_int2(src, combo);
}

// ---------------- fused: aggregate + conv GEMM (+res) + BN stats partials ----------------
// float4/lane, 4 edges per gather instruction (lane group g=lane>>4 handles edge j+g),
// butterfly-reduce groups, W in VGPRs, shfl-GEMM.
__global__ __launch_bounds__(256, 4) void k_conv_fused(
        const float* __restrict__ gsrc, const float* res,
        const int* __restrict__ rp, const int2* __restrict__ edges,
        const float* __restrict__ ctab,
        const float* __restrict__ W, const float* __restrict__ bvec,
        float* __restrict__ out, float* __restrict__ statsPart) {
    __shared__ float sRed[2][CONV_WPB][64];
    int lane = threadIdx.x & 63;
    int wv = threadIdx.x >> 6;
    int grp = lane >> 4;          // edge subgroup 0..3
    int qc  = (lane & 15) * 4;    // base channel of this lane's float4
    float wreg[64];
    #pragma unroll
    for (int k = 0; k < 64; ++k) wreg[k] = W[k * 64 + lane];
    float bias = bvec[lane];
    int w = blockIdx.x * CONV_WPB + wv;
    int n0 = w * CONV_CHUNK;
    int n1 = min(n0 + CONV_CHUNK, NN);
    float psum = 0.f, psq = 0.f;
    for (int n = n0; n < n1; ++n) {
        int beg = rp[n], end = rp[n + 1];
        int deg = end - beg;
        float ax = 0.f, ay = 0.f, az = 0.f, aw = 0.f;
        for (int base = 0; base < deg; base += 64) {
            int cnt = min(64, deg - base);
            int2 me = edges[beg + base + min(lane, cnt - 1)];
            int j = 0;
            for (; j + 8 <= cnt; j += 8) {
                int i0 = j + grp, i1 = j + 4 + grp;
                int s0 = __shfl(me.x, i0, 64), c0 = __shfl(me.y, i0, 64);
                int s1 = __shfl(me.x, i1, 64), c1 = __shfl(me.y, i1, 64);
                float4 h0 = *(const float4*)(gsrc + (size_t)s0 * 64 + qc);
                float4 t0 = *(const float4*)(ctab + (size_t)c0 * 64 + qc);
                float4 h1 = *(const float4*)(gsrc + (size_t)s1 * 64 + qc);
                float4 t1 = *(const float4*)(ctab + (size_t)c1 * 64 + qc);
                ax += fmaxf(h0.x + t0.x, 0.f) + fmaxf(h1.x + t1.x, 0.f);
                ay += fmaxf(h0.y + t0.y, 0.f) + fmaxf(h1.y + t1.y, 0.f);
                az += fmaxf(h0.z + t0.z, 0.f) + fmaxf(h1.z + t1.z, 0.f);
                aw += fmaxf(h0.w + t0.w, 0.f) + fmaxf(h1.w + t1.w, 0.f);
            }
            for (; j < cnt; j += 4) {
                int i0 = j + grp;
                bool valid = i0 < cnt;
                int sl = valid ? i0 : 0;
                int s0 = __shfl(me.x, sl, 64), c0 = __shfl(me.y, sl, 64);
                float4 h0 = *(const float4*)(gsrc + (size_t)s0 * 64 + qc);
                float4 t0 = *(const float4*)(ctab + (size_t)c0 * 64 + qc);
                if (valid) {
                    ax += fmaxf(h0.x + t0.x, 0.f);
                    ay += fmaxf(h0.y + t0.y, 0.f);
                    az += fmaxf(h0.z + t0.z, 0.f);
                    aw += fmaxf(h0.w + t0.w, 0.f);
                }
            }
        }
        // butterfly-reduce across the 4 groups (lane bits 4,5); replicates result
        ax += __shfl_xor(ax, 16, 64); ay += __shfl_xor(ay, 16, 64);
        az += __shfl_xor(az, 16, 64); aw += __shfl_xor(aw, 16, 64);
        ax += __shfl_xor(ax, 32, 64); ay += __shfl_xor(ay, 32, 64);
        az += __shfl_xor(az, 32, 64); aw += __shfl_xor(aw, 32, 64);
        float4 sv = *(const float4*)(gsrc + (size_t)n * 64 + qc);
        float epsd = (float)deg * EPS_GEN;
        float vx = sv.x + ax + epsd;
        float vy = sv.y + ay + epsd;
        float vz = sv.z + az + epsd;
        float vw = sv.w + aw + epsd;
        float r = bias;
        #pragma unroll
        for (int k = 0; k < 16; ++k) {
            r = fmaf(__shfl(vx, k, 64), wreg[4 * k + 0], r);
            r = fmaf(__shfl(vy, k, 64), wreg[4 * k + 1], r);
            r = fmaf(__shfl(vz, k, 64), wreg[4 * k + 2], r);
            r = fmaf(__shfl(vw, k, 64), wreg[4 * k + 3], r);
        }
        if (res) r += res[(size_t)n * 64 + lane];
        out[(size_t)n * 64 + lane] = r;
        psum += r; psq = fmaf(r, r, psq);
    }
    sRed[0][wv][lane] = psum;
    sRed[1][wv][lane] = psq;
    __syncthreads();
    if (threadIdx.x < 64) {
        float s = 0.f, q = 0.f;
        #pragma unroll
        for (int i = 0; i < CONV_WPB; ++i) { s += sRed[0][i][threadIdx.x]; q += sRed[1][i][threadIdx.x]; }
        float* sp = statsPart + (blockIdx.x & (SLOTS - 1)) * 128;
        atomicAdd(&sp[threadIdx.x], s);
        atomicAdd(&sp[64 + threadIdx.x], q);
    }
}

// fold 64 slot-partials -> ms[0..63]=mu, ms[64..127]=rstd
__global__ void k_finstats(const float* __restrict__ sp, float rows_inv, float* __restrict__ ms) {
    int lane = threadIdx.x;
    float s = 0.f, q = 0.f;
    for (int i = 0; i < SLOTS; ++i) { s += sp[i * 128 + lane]; q += sp[i * 128 + 64 + lane]; }
    float mu = s * rows_inv;
    float var = q * rows_inv - mu * mu;
    ms[lane] = mu;
    ms[64 + lane] = rsqrtf(var + EPS_BN);
}

// ---------------- BN / pooling ----------------

// h2 = relu(bn(h)); vt[batch[n]] += h2[n], run-length aggregated; chunk=16 nodes/wave
__global__ void k_bn_relu_vt2(const float* __restrict__ h, const float* __restrict__ ms,
                              const float* __restrict__ gamma, const float* __restrict__ beta,
                              const int* __restrict__ batch,
                              float* __restrict__ h2, float* __restrict__ vt) {
    int lane = threadIdx.x & 63;
    int w = blockIdx.x * 4 + (threadIdx.x >> 6);
    int n0 = w * 16;
    if (n0 >= NN) return;
    int n1 = min(n0 + 16, NN);
    float mu = ms[lane];
    float inv = ms[64 + lane] * gamma[lane];
    float bet = beta[lane];
    float acc = 0.f;
    int gcur = batch[n0];
    for (int n = n0; n < n1; ++n) {
        float v = fmaxf((h[(size_t)n * 64 + lane] - mu) * inv + bet, 0.f);
        h2[(size_t)n * 64 + lane] = v;
        int g = batch[n];
        if (g != gcur) {
            atomicAdd(&vt[(size_t)gcur * 64 + lane], acc);
            acc = 0.f; gcur = g;
        }
        acc += v;
    }
    atomicAdd(&vt[(size_t)gcur * 64 + lane], acc);
}

// VN GEMM over 512 rows: out = (bnrelu?(in) + addterm) @ W + b; writes out-stats.
__global__ void k_vn_gemm(const float* __restrict__ in, const float* in_stats,
                          const float* in_g, const float* in_be,
                          const float* add, const float* add_stats,
                          const float* add_g, const float* add_be,
                          const float* __restrict__ W, const float* __restrict__ bvec,
                          float* __restrict__ out, float* __restrict__ out_stats) {
    __shared__ float sW[4096];
    __shared__ float sRed[2][4][64];
    for (int i = threadIdx.x; i < 4096; i += 256) sW[i] = W[i];
    __syncthreads();
    int lane = threadIdx.x & 63, wv = threadIdx.x >> 6;
    int w = blockIdx.x * 4 + wv;          // 32 waves, 16 rows each
    float imu = 0.f, iinv = 0.f, ibe = 0.f;
    if (in_stats) {
        float mu = in_stats[lane] * (1.f / GG);
        float var = in_stats[64 + lane] * (1.f / GG) - mu * mu;
        imu = mu; iinv = rsqrtf(var + EPS_BN) * in_g[lane]; ibe = in_be[lane];
    }
    float amu = 0.f, ainv = 0.f, abe = 0.f;
    if (add && add_stats) {
        float mu = add_stats[lane] * (1.f / GG);
        float var = add_stats[64 + lane] * (1.f / GG) - mu * mu;
        amu = mu; ainv = rsqrtf(var + EPS_BN) * add_g[lane]; abe = add_be[lane];
    }
    float psum = 0.f, psq = 0.f;
    for (int r = w * 16; r < w * 16 + 16; ++r) {
        float va = in[r * 64 + lane];
        if (in_stats) va = fmaxf((va - imu) * iinv + ibe, 0.f);
        if (add) {
            float av;
            if (add_stats) av = fmaxf((add[r * 64 + lane] - amu) * ainv + abe, 0.f);
            else av = add[lane];
            va += av;
        }
        float acc = bvec[lane];
        #pragma unroll
        for (int k = 0; k < 64; ++k)
            acc = fmaf(__shfl(va, k, 64), sW[k * 64 + lane], acc);
        out[r * 64 + lane] = acc;
        psum += acc; psq = fmaf(acc, acc, psq);
    }
    sRed[0][wv][lane] = psum;
    sRed[1][wv][lane] = psq;
    __syncthreads();
    if (threadIdx.x < 64) {
        float s = 0.f, q = 0.f;
        #pragma unroll
        for (int i = 0; i < 4; ++i) { s += sRed[0][i][threadIdx.x]; q += sRed[1][i][threadIdx.x]; }
        atomicAdd(&out_stats[threadIdx.x], s);
        atomicAdd(&out_stats[64 + threadIdx.x], q);
    }
}

// h2[n] += bnrelu(t2)[batch[n]]
__global__ void k_add_vn2(float* __restrict__ h2, const float* __restrict__ t2,
                          const float* __restrict__ stats2,
                          const float* __restrict__ g2, const float* __restrict__ be2,
                          const int* __restrict__ batch) {
    int tid = blockIdx.x * blockDim.x + threadIdx.x;
    int n = tid >> 6, c = tid & 63;
    if (n >= NN) return;
    float mu = stats2[c] * (1.f / GG);
    float var = stats2[64 + c] * (1.f / GG) - mu * mu;
    float inv = rsqrtf(var + EPS_BN) * g2[c];
    float v = fmaxf((t2[(size_t)batch[n] * 64 + c] - mu) * inv + be2[c], 0.f);
    h2[tid] += v;
}

// final BN + mean-pool, run-length aggregated; chunk=32
__global__ void k_pool2(const float* __restrict__ h, const float* __restrict__ ms,
                        const float* __restrict__ gamma, const float* __restrict__ beta,
                        const int* __restrict__ batch,
                        float* __restrict__ out, float* __restrict__ cnt) {
    int lane = threadIdx.x & 63;
    int w = blockIdx.x * 4 + (threadIdx.x >> 6);
    int n0 = w * 32;
    if (n0 >= NN) return;
    int n1 = min(n0 + 32, NN);
    float mu = ms[lane];
    float inv = ms[64 + lane] * gamma[lane];
    float bet = beta[lane];
    float acc = 0.f;
    int run = 0;
    int gcur = batch[n0];
    for (int n = n0; n < n1; ++n) {
        float v = (h[(size_t)n * 64 + lane] - mu) * inv + bet;
        int g = batch[n];
        if (g != gcur) {
            atomicAdd(&out[(size_t)gcur * 64 + lane], acc);
            if (lane == 0) atomicAdd(&cnt[gcur], (float)run);
            acc = 0.f; run = 0; gcur = g;
        }
        acc += v; run++;
    }
    atomicAdd(&out[(size_t)gcur * 64 + lane], acc);
    if (lane == 0) atomicAdd(&cnt[gcur], (float)run);
}

__global__ void k_div(float* __restrict__ out, const float* __restrict__ cnt) {
    int tid = blockIdx.x * blockDim.x + threadIdx.x;
    if (tid >= GH) return;
    out[tid] /= fmaxf(cnt[tid >> 6], 1.0f);
}

extern "C" void kernel_launch(void* const* d_in, const int* in_sizes, int n_in,
                              void* d_out, int out_size, void* d_ws, size_t ws_size,
                              hipStream_t stream) {
    const float* atom_table = (const float*)d_in[0];
    const float* bond_table = (const float*)d_in[1];
    const float* vn0   = (const float*)d_in[2];
    const float* gcn_W = (const float*)d_in[3];
    const float* gcn_b = (const float*)d_in[4];
    const float* ng    = (const float*)d_in[5];
    const float* nb    = (const float*)d_in[6];
    const float* vn_W1 = (const float*)d_in[7];
    const float* vn_b1 = (const float*)d_in[8];
    const float* vn_g1 = (const float*)d_in[9];
    const float* vn_be1= (const float*)d_in[10];
    const float* vn_W2 = (const float*)d_in[11];
    const float* vn_b2 = (const float*)d_in[12];
    const float* vn_g2 = (const float*)d_in[13];
    const float* vn_be2= (const float*)d_in[14];
    const int* x          = (const int*)d_in[15];
    const int* edge_index = (const int*)d_in[16];
    const int* edge_attr  = (const int*)d_in[17];
    const int* batch      = (const int*)d_in[18];

    float* ws = (float*)d_ws;
    float* hA  = ws;                     // NH (encoder out / h2)
    float* hB  = ws + (size_t)NH;        // NH (running h)
    float* h2  = hA;
    float* vt  = ws + (size_t)2 * NH;    // GH
    float* t1  = vt + GH;                // GH
    float* t2  = t1 + GH;                // GH
    float* convStatsP = t2 + GH;                       // 7 * SLOTS * 128
    float* msAll      = convStatsP + 7 * SLOTS * 128;  // 7 * 128 (finalized mu/rstd)
    float* vn1Stats   = msAll + 7 * 128;               // 6*128
    float* vn2Stats   = vn1Stats + 6 * 128;            // 6*128
    float* cnt    = vn2Stats + 6 * 128;  // GG
    float* ctab   = cnt + GG;            // 60*64
    int*   rp     = (int*)(ctab + 60 * 64);  // NN+1
    int*   cur    = rp + (NN + 1);           // NN
    int*   part   = cur + NN;                // 128
    int*   pad    = part + 128;
    int2*  edges  = (int2*)((((uintptr_t)pad) + 7) & ~(uintptr_t)7);

    const int blkN = NH / 256;               // 25000
    const int blkG = (GH + 255) / 256;       // 128
    const int blkE = (EE + 255) / 256;       // 3907
    const int blkRL = ((NN + 15) / 16 + 3) / 4;
    const int blkPL = ((NN + 31) / 32 + 3) / 4;
    float* outp = (float*)d_out;

    k_atom_enc<<<blkN, 256, 0, stream>>>(atom_table, vn0, x, hA);
    k_ctab<<<60, 64, 0, stream>>>(bond_table, ctab);
    hipMemsetAsync(convStatsP, 0, (7 * SLOTS * 128 + 7 * 128 + 12 * 128) * 4, stream);

    // ---- CSR build ----
    hipMemsetAsync(cur, 0, (size_t)NN * 4, stream);
    k_count<<<blkE, 256, 0, stream>>>(edge_index, cur);
    k_scan1<<<SCAN_BLKS, 256, 0, stream>>>(cur, rp, part);
    k_scan2<<<1, 128, 0, stream>>>(part);
    k_scan3<<<(NN + 255) / 256, 256, 0, stream>>>(rp, part);
    hipMemsetAsync(cur, 0, (size_t)NN * 4, stream);
    k_fill<<<blkE, 256, 0, stream>>>(edge_index, edge_attr, rp, cur, edges);

    // ---- layer 0 ----
    k_conv_fused<<<CONV_BLOCKS, 256, 0, stream>>>(hA, nullptr, rp, edges, ctab,
                                                  gcn_W, gcn_b, hB, convStatsP);

    for (int l = 1; l < LL; ++l) {
        k_finstats<<<1, 64, 0, stream>>>(convStatsP + (size_t)(l - 1) * SLOTS * 128,
                                         1.f / NN, msAll + (size_t)(l - 1) * 128);
        hipMemsetAsync(vt, 0, (size_t)GH * 4, stream);
        k_bn_relu_vt2<<<blkRL, 256, 0, stream>>>(hB, msAll + (size_t)(l - 1) * 128,
                                                 ng + (size_t)(l - 1) * HH,
                                                 nb + (size_t)(l - 1) * HH, batch, h2, vt);
        // t1 = (vt + vn_prev) @ W1 + b1 ; vn_prev = l==1 ? vn0 : bnrelu(t2, stats2[l-2])
        if (l == 1)
            k_vn_gemm<<<8, 256, 0, stream>>>(vt, nullptr, nullptr, nullptr,
                                             vn0, nullptr, nullptr, nullptr,
                                             vn_W1, vn_b1, t1, vn1Stats);
        else
            k_vn_gemm<<<8, 256, 0, stream>>>(vt, nullptr, nullptr, nullptr,
                                             t2, vn2Stats + (size_t)(l - 2) * 128,
                                             vn_g2 + (size_t)(l - 2) * HH,
                                             vn_be2 + (size_t)(l - 2) * HH,
                                             vn_W1 + (size_t)(l - 1) * 4096,
                                             vn_b1 + (size_t)(l - 1) * HH, t1,
                                             vn1Stats + (size_t)(l - 1) * 128);
        // t2 = bnrelu(t1) @ W2 + b2
        k_vn_gemm<<<8, 256, 0, stream>>>(t1, vn1Stats + (size_t)(l - 1) * 128,
                                         vn_g1 + (size_t)(l - 1) * HH,
                                         vn_be1 + (size_t)(l - 1) * HH,
                                         nullptr, nullptr, nullptr, nullptr,
                                         vn_W2 + (size_t)(l - 1) * 4096,
                                         vn_b2 + (size_t)(l - 1) * HH, t2,
                                         vn2Stats + (size_t)(l - 1) * 128);
        // h2 += bnrelu(t2)[batch]
        k_add_vn2<<<blkN, 256, 0, stream>>>(h2, t2, vn2Stats + (size_t)(l - 1) * 128,
                                            vn_g2 + (size_t)(l - 1) * HH,
                                            vn_be2 + (size_t)(l - 1) * HH, batch);

        k_conv_fused<<<CONV_BLOCKS, 256, 0, stream>>>(h2, hB, rp, edges, ctab,
                                                      gcn_W + (size_t)l * 4096,
                                                      gcn_b + (size_t)l * HH, hB,
                                                      convStatsP + (size_t)l * SLOTS * 128);
    }

    // ---- final BN + mean pool ----
    k_finstats<<<1, 64, 0, stream>>>(convStatsP + (size_t)6 * SLOTS * 128,
                                     1.f / NN, msAll + (size_t)6 * 128);
    hipMemsetAsync(outp, 0, (size_t)GH * 4, stream);
    hipMemsetAsync(cnt, 0, (size_t)GG * 4, stream);
    k_pool2<<<blkPL, 256, 0, stream>>>(hB, msAll + (size_t)6 * 128,
                                       ng + (size_t)6 * HH, nb + (size_t)6 * HH,
                                       batch, outp, cnt);
    k_div<<<blkG, 256, 0, stream>>>(outp, cnt);
}